// Round 7
// baseline (747.848 us; speedup 1.0000x reference)
//
#include <hip/hip_runtime.h>

// ---------------- helpers ----------------
__device__ __forceinline__ unsigned short f2bf(float f) {
    union { float f; unsigned u; } v; v.f = f;
    unsigned u = v.u;
    unsigned r = (u + 0x7fffu + ((u >> 16) & 1u)) >> 16;
    return (unsigned short)r;
}
__device__ __forceinline__ float bfup(int x) {
    union { unsigned u; float f; } v; v.u = ((unsigned)(unsigned short)x) << 16; return v.f;
}

typedef __attribute__((ext_vector_type(8))) short short8;
typedef __attribute__((ext_vector_type(4))) float floatx4;

// dims
#define Bn 4
#define Ln 256
#define Hn 768
#define Tn 16
#define PITCH 288   // k_hidden3 bf16 pitch: 2-way (free) LDS aliasing
#define NBLK 512    // k_mid grid: 2 blocks/CU co-resident guaranteed (8KB LDS, <=256 VGPR)

// ---------------- fused mid-pipeline: args ----------------
struct MidArgs {
    const float* x;
    const float* g0; const float* b0;
    float* emb;
    const float* W1; unsigned short* w1t;
    const float* Wc; const float* Wc1; const float* g1; const float* b1;
    unsigned short* wfg;
    const int* ast; const int* aed; const int* ost; const int* oed; const int* sid;
    float* nf; float* hedge;
    const float* Wtp; const float* btp;
    const float* E; const float* Wat; const float* bat;
    const float* Wg; const float* bg;
    float* abm;
    unsigned* bar;   // 2 barriers x 160 u32 (8 padded subs + master + go), memset 0
};

// 2-level grid barrier: 8 padded sub-counters (64B apart) -> master -> go flag.
// Arrival RMWs parallelize across 8 cache lines; only `wait` blocks poll go
// (sleep ~1.7us). Prior writes released by threadfence + RMW chain; readers
// acquire via go-poll (+fence) then __syncthreads broadcast. Same primitive
// pattern as rounds 3/5 (both passed); bounded spin avoids wedging.
__device__ __forceinline__ void gbar2(unsigned* base, unsigned subQuota, int blk, int tid, bool wait) {
    __syncthreads();
    if (tid == 0) {
        __threadfence();
        unsigned a = __hip_atomic_fetch_add(base + (blk & 7) * 16, 1u, __ATOMIC_ACQ_REL, __HIP_MEMORY_SCOPE_AGENT) + 1u;
        if (a == subQuota) {
            unsigned m = __hip_atomic_fetch_add(base + 128, 1u, __ATOMIC_ACQ_REL, __HIP_MEMORY_SCOPE_AGENT) + 1u;
            if (m == 8u) __hip_atomic_store(base + 129, 1u, __ATOMIC_RELEASE, __HIP_MEMORY_SCOPE_AGENT);
        }
        if (wait) {
            unsigned spins = 0;
            while (!__hip_atomic_load(base + 129, __ATOMIC_ACQUIRE, __HIP_MEMORY_SCOPE_AGENT)) {
                __builtin_amdgcn_s_sleep(64);
                if (++spins > 20000u) break;   // ~34ms safety valve
            }
            __threadfence();
        }
    }
    __syncthreads();
}

// ---- phase-1 node job: span-LN -> xv (LDS) -> nf row = xv @ Wtp + btp ----
__device__ __forceinline__ void node_job(const MidArgs& A, int n, int tid, float* sh) {
    float* xv    = sh;          // [1539]
    float* rstdA = sh + 1540;   // [3]
    float* rstdO = sh + 1543;   // [3]
    float* cc    = sh + 1546;   // [2]
    float* sred  = sh + 1548;   // [4]
    float* qred  = sh + 1552;   // [4]
    int b = n >> 4;
    int a_st = A.ast[n], a_ed = A.aed[n], o_st = A.ost[n], o_ed = A.oed[n], s_id = A.sid[n];
    int na = a_ed - a_st + 1, no2 = o_ed - o_st + 1;
    if (tid == 0) { cc[0] = 0.f; cc[1] = 0.f; }
    __syncthreads();
    for (int slot = 0; slot < 6; ++slot) {
        int isA = slot < 3;
        int off = isA ? slot : slot - 3;
        int cnt = isA ? na : no2;
        int row = (isA ? a_st : o_st) + off;
        if (off < cnt) {
            const float* xr = A.x + (size_t)(b * 256 + row) * Hn;
            float v0 = xr[tid], v1 = xr[tid + 256], v2 = xr[tid + 512];
            float s = v0 + v1 + v2;
            float q = v0 * v0 + v1 * v1 + v2 * v2;
            for (int o = 32; o > 0; o >>= 1) { s += __shfl_down(s, o); q += __shfl_down(q, o); }
            if ((tid & 63) == 0) { sred[tid >> 6] = s; qred[tid >> 6] = q; }
        }
        __syncthreads();
        if (off < cnt && tid == 0) {
            float S = sred[0] + sred[1] + sred[2] + sred[3];
            float Q = qred[0] + qred[1] + qred[2] + qred[3];
            float mean = S * (1.f / 768.f);
            float rstd = rsqrtf(Q * (1.f / 768.f) - mean * mean + 1e-5f);
            if (isA) { rstdA[off] = rstd; cc[0] += mean * rstd; }
            else     { rstdO[off] = rstd; cc[1] += mean * rstd; }
        }
        __syncthreads();
    }
    float ai = 1.f / (float)na, oi = 1.f / (float)no2;
    float cA = cc[0] * ai, cO = cc[1] * oi;
    const float* eb = A.x + (size_t)b * Ln * Hn;
    for (int r = tid; r < 1539; r += 256) {
        float v;
        if (r < 768) {
            float sa = 0.f;
            for (int l = 0; l < na; ++l) sa = fmaf(eb[(a_st + l) * Hn + r], rstdA[l], sa);
            v = fmaf(A.g0[r], sa * ai - cA, A.b0[r]);
        } else if (r < 1536) {
            int h = r - 768;
            float so = 0.f;
            for (int l = 0; l < no2; ++l) so = fmaf(eb[(o_st + l) * Hn + h], rstdO[l], so);
            v = fmaf(A.g0[h], so * oi - cO, A.b0[h]);
        } else {
            v = (s_id - 2 == r - 1536) ? 1.f : 0.f;
        }
        xv[r] = v;
    }
    __syncthreads();
    // nf row: coalesced row-major Wtp reads, LDS-broadcast xv
    int c0 = tid, c1 = tid + 256, c2 = tid + 512;
    float v0 = A.btp[c0], v1 = A.btp[c1], v2 = A.btp[c2];
#pragma unroll 4
    for (int k = 0; k < 1539; ++k) {
        float a = xv[k];
        const float* wr = A.Wtp + (size_t)k * 768;
        v0 = fmaf(a, wr[c0], v0);
        v1 = fmaf(a, wr[c1], v1);
        v2 = fmaf(a, wr[c2], v2);
    }
    float* nr = A.nf + (size_t)n * Hn;
    nr[c0] = v0; nr[c1] = v1; nr[c2] = v2;
}

// ---- phase-2 graph chain (one block per node): attn -> agg -> skinny2 -> scatter ----
__device__ __forceinline__ void graph_chain(const MidArgs& A, int n, int tid, float* sh) {
    int b = n >> 4, t = n & 15;
    float* agg_lds = sh;                    // [1536]
    float* n2S  = sh + 1536;                // [16]
    float* qS   = sh + 1552;                // [16]
    float* misc = sh + 1568;                // [3] pT, rr0, rr1
    float* wss  = sh + 1572;                // [16]
    float* aes  = sh + 1588;                // [2]
    float* hsh  = sh + 1590;                // [2] hedge, hasin_t
    unsigned* m0b = (unsigned*)(sh + 1592); // [16]
    unsigned* m1b = (unsigned*)(sh + 1608); // [16]
    int* asts = (int*)(sh + 1624); int* aeds = (int*)(sh + 1640);
    int* osts = (int*)(sh + 1656); int* oeds = (int*)(sh + 1672);
    const float* nfb = A.nf + (size_t)b * 16 * Hn;
    if (tid < 16) {
        int m = b * 16 + tid;
        asts[tid] = A.ast[m]; aeds[tid] = A.aed[m];
        osts[tid] = A.ost[m]; oeds[tid] = A.oed[m];
        m0b[tid] = 0u; m1b[tid] = 0u;
    }
    // phase A: group s owns source node s -> n2, q[s]; group 0: p[t]; groups 1,2: rr
    int s = tid >> 4, l = tid & 15;
    const float* vs = nfb + (size_t)s * Hn;
    const float* vt = nfb + (size_t)t * Hn;
    const float* er = A.E + ((s == 2) ? 768 : 0);
    float n2 = 0.f, qq = 0.f, pp = 0.f, rr = 0.f;
#pragma unroll 4
    for (int h = l; h < 768; h += 16) {
        float v = vs[h];
        n2 = fmaf(v, v, n2);
        float lv = v > 0.f ? v : 0.2f * v;
        qq = fmaf(lv, A.Wat[768 + h], qq);
        if (s == 0) { float tv = vt[h]; float lt = tv > 0.f ? tv : 0.2f * tv; pp = fmaf(lt, A.Wat[h], pp); }
        if (s == 1 || s == 2) { float ev = er[h]; float le = ev > 0.f ? ev : 0.2f * ev; rr = fmaf(le, A.Wat[1536 + h], rr); }
    }
    for (int o = 8; o > 0; o >>= 1) {
        n2 += __shfl_down(n2, o); qq += __shfl_down(qq, o);
        pp += __shfl_down(pp, o); rr += __shfl_down(rr, o);
    }
    if (l == 0) {
        n2S[s] = n2; qS[s] = qq;
        if (s == 0) misc[0] = pp;
        if (s == 1) misc[1] = rr;
        if (s == 2) misc[2] = rr;
    }
    __syncthreads();
    // all-pairs sim + span-equality masks (gives hedge without cross-block sync)
    {
        int i = tid >> 4, j = tid & 15;
        const float4* ri = (const float4*)(nfb + (size_t)i * Hn);
        const float4* rj = (const float4*)(nfb + (size_t)j * Hn);
        float dot = 0.f;
#pragma unroll 8
        for (int h4 = 0; h4 < 192; ++h4) {
            float4 a = ri[h4], c = rj[h4];
            dot = fmaf(a.x, c.x, dot); dot = fmaf(a.y, c.y, dot);
            dot = fmaf(a.z, c.z, dot); dot = fmaf(a.w, c.w, dot);
        }
        float sim = dot / (fmaxf(sqrtf(n2S[i]), 1e-8f) * fmaxf(sqrtf(n2S[j]), 1e-8f));
        bool ok = (sim > 0.f) && (i != j);
        if (ok && asts[i] == asts[j] && aeds[i] == aeds[j]) atomicOr(&m0b[i], 1u << j);
        if (ok && osts[i] == osts[j] && oeds[i] == oeds[j]) atomicOr(&m1b[i], 1u << j);
    }
    __syncthreads();
    if (tid == 0) {
        unsigned any = 0;
#pragma unroll
        for (int k2 = 0; k2 < 16; ++k2) any |= m0b[k2] | m1b[k2];
        hsh[0] = any ? 1.f : 0.f;
        unsigned row = m0b[t] | m1b[t];   // masks exactly symmetric: row t == column t
        hsh[1] = row ? 1.f : 0.f;
        A.hedge[b] = any ? 1.f : 0.f;     // identical dup-writes across the batch's blocks
    }
    // phase B: lane-parallel masked softmax over 32 (s,e) entries (wave 0)
    if (tid < 64) {
        int ss = tid >> 1, e = tid & 1;
        bool valid = tid < 32;
        int ssc = ss & 15;
        bool edge;
        if (e == 0) edge = valid && (((m0b[ssc] >> t) & 1u) != 0u);
        else        edge = valid && (((m1b[ssc] >> t) & 1u) != 0u);
        float sc = edge ? (misc[0] + qS[ssc] + (e ? misc[2] : misc[1]) + A.bat[0]) : -1e9f;
        float mx = sc;
        for (int o = 16; o > 0; o >>= 1) mx = fmaxf(mx, __shfl_xor(mx, o));
        float ex = __expf(sc - mx);
        float sum = ex;
        for (int o = 16; o > 0; o >>= 1) sum += __shfl_xor(sum, o);
        float w = ex / sum;
        float wtot = w + __shfl_xor(w, 1);
        if (valid && e == 0) wss[ss] = wtot;
        float a0 = (valid && e == 0) ? w : 0.f;
        float a1 = (valid && e == 1) ? w : 0.f;
        for (int o = 16; o > 0; o >>= 1) { a0 += __shfl_xor(a0, o); a1 += __shfl_xor(a1, o); }
        if (tid == 0) { aes[0] = a0; aes[1] = a1; }
    }
    __syncthreads();
    // phase C: aggregation row into LDS (nf rows are L2-hot)
    float ae0 = aes[0], ae1 = aes[1];
    for (int f = tid; f < 768; f += 256) {
        float acc = 0.f;
#pragma unroll
        for (int s16 = 0; s16 < 16; ++s16) acc = fmaf(wss[s16], nfb[(size_t)s16 * Hn + f], acc);
        agg_lds[f] = acc;
        agg_lds[768 + f] = ae0 * A.E[f] + ae1 * A.E[768 + f];
    }
    __syncthreads();
    // skinny2 (in-block) + scatter-add
    if (hsh[0] != 0.f) {
        bool hi = hsh[1] != 0.f;
        int center = (asts[t] + osts[t]) >> 1;
        float* dst = A.emb + (size_t)(b * Ln + center) * Hn;
        int c0 = tid, c1 = tid + 256, c2 = tid + 512;
        float v0, v1, v2;
        if (hi) {
            v0 = A.bg[c0]; v1 = A.bg[c1]; v2 = A.bg[c2];
#pragma unroll 4
            for (int k = 0; k < 1536; ++k) {
                float a = agg_lds[k];
                const float* wr = A.Wg + (size_t)k * 768;
                v0 = fmaf(a, wr[c0], v0);
                v1 = fmaf(a, wr[c1], v1);
                v2 = fmaf(a, wr[c2], v2);
            }
            v0 = fmaxf(v0, 0.f); v1 = fmaxf(v1, 0.f); v2 = fmaxf(v2, 0.f);
        } else {
            const float* nt_ = nfb + (size_t)t * Hn;
            v0 = nt_[c0]; v1 = nt_[c1]; v2 = nt_[c2];
        }
        atomicAdd(&dst[c0], v0);
        atomicAdd(&dst[c1], v1);
        atomicAdd(&dst[c2], v2);
    }
}

// gemm wave: one 32x32 tile of abm[1024][512] = bf16(emb) @ w1t^T
__device__ __forceinline__ void gemm_wave(const float* __restrict__ emb,
                                          const unsigned short* __restrict__ w1t,
                                          float* __restrict__ abm,
                                          int wid, int lane) {
    int m0 = (wid >> 4) * 32;
    int n0 = (wid & 15) * 32;
    int r = lane & 15, g = lane >> 4;
    const float* Af0 = emb + (size_t)(m0 + r) * 768 + g * 8;
    const float* Af1 = emb + (size_t)(m0 + 16 + r) * 768 + g * 8;
    const short8* Bp0 = (const short8*)(w1t + (size_t)(n0 + r) * 768 + g * 8);
    const short8* Bp1 = (const short8*)(w1t + (size_t)(n0 + 16 + r) * 768 + g * 8);
    floatx4 acc00 = {0.f, 0.f, 0.f, 0.f}, acc01 = {0.f, 0.f, 0.f, 0.f};
    floatx4 acc10 = {0.f, 0.f, 0.f, 0.f}, acc11 = {0.f, 0.f, 0.f, 0.f};
#pragma unroll 4
    for (int ks = 0; ks < 768; ks += 32) {
        float4 x0 = *(const float4*)(Af0 + ks);
        float4 x1 = *(const float4*)(Af0 + ks + 4);
        float4 y0 = *(const float4*)(Af1 + ks);
        float4 y1 = *(const float4*)(Af1 + ks + 4);
        short8 a0, a1;
        union { float f; unsigned u; } cv;
#define PK(dst, idx, val) { cv.f = (val); dst[idx] = (short)((cv.u + 0x8000u) >> 16); }
        PK(a0, 0, x0.x) PK(a0, 1, x0.y) PK(a0, 2, x0.z) PK(a0, 3, x0.w)
        PK(a0, 4, x1.x) PK(a0, 5, x1.y) PK(a0, 6, x1.z) PK(a0, 7, x1.w)
        PK(a1, 0, y0.x) PK(a1, 1, y0.y) PK(a1, 2, y0.z) PK(a1, 3, y0.w)
        PK(a1, 4, y1.x) PK(a1, 5, y1.y) PK(a1, 6, y1.z) PK(a1, 7, y1.w)
#undef PK
        short8 b0 = Bp0[ks >> 3];
        short8 b1 = Bp1[ks >> 3];
        acc00 = __builtin_amdgcn_mfma_f32_16x16x32_bf16(a0, b0, acc00, 0, 0, 0);
        acc01 = __builtin_amdgcn_mfma_f32_16x16x32_bf16(a0, b1, acc01, 0, 0, 0);
        acc10 = __builtin_amdgcn_mfma_f32_16x16x32_bf16(a1, b0, acc10, 0, 0, 0);
        acc11 = __builtin_amdgcn_mfma_f32_16x16x32_bf16(a1, b1, acc11, 0, 0, 0);
    }
#pragma unroll
    for (int t = 0; t < 4; ++t) {
        int row = g * 4 + t;
        abm[(size_t)(m0 + row) * 512 + n0 + r]           = acc00[t];
        abm[(size_t)(m0 + row) * 512 + n0 + 16 + r]      = acc01[t];
        abm[(size_t)(m0 + 16 + row) * 512 + n0 + r]      = acc10[t];
        abm[(size_t)(m0 + 16 + row) * 512 + n0 + 16 + r] = acc11[t];
    }
}

// phase-3: recompute abm rows dirtied by scatter (<=64 rows); dup writers identical
__device__ __forceinline__ void gemm_fix(const MidArgs& A, int n, int tid, float* sh) {
    int b = n >> 4;
    if (A.hedge[b] == 0.f) return;   // block-uniform
    int r = b * Ln + ((A.ast[n] + A.ost[n]) >> 1);
    const float* er = A.emb + (size_t)r * Hn;
    for (int h = tid; h < 768; h += 256) sh[h] = bfup(f2bf(er[h]));
    __syncthreads();
    int c0 = tid, c1 = tid + 256;
    const short8* w0 = (const short8*)(A.w1t + (size_t)c0 * 768);
    const short8* w1p = (const short8*)(A.w1t + (size_t)c1 * 768);
    float a0 = 0.f, a1 = 0.f, a2 = 0.f, a3 = 0.f;
    float b0_ = 0.f, b1_ = 0.f, b2_ = 0.f, b3_ = 0.f;
    for (int k8 = 0; k8 < 96; ++k8) {
        short8 wa = w0[k8], wb = w1p[k8];
        int kb = k8 * 8;
        a0 = fmaf(sh[kb + 0], bfup(wa[0]), a0);
        a1 = fmaf(sh[kb + 1], bfup(wa[1]), a1);
        a2 = fmaf(sh[kb + 2], bfup(wa[2]), a2);
        a3 = fmaf(sh[kb + 3], bfup(wa[3]), a3);
        a0 = fmaf(sh[kb + 4], bfup(wa[4]), a0);
        a1 = fmaf(sh[kb + 5], bfup(wa[5]), a1);
        a2 = fmaf(sh[kb + 6], bfup(wa[6]), a2);
        a3 = fmaf(sh[kb + 7], bfup(wa[7]), a3);
        b0_ = fmaf(sh[kb + 0], bfup(wb[0]), b0_);
        b1_ = fmaf(sh[kb + 1], bfup(wb[1]), b1_);
        b2_ = fmaf(sh[kb + 2], bfup(wb[2]), b2_);
        b3_ = fmaf(sh[kb + 3], bfup(wb[3]), b3_);
        b0_ = fmaf(sh[kb + 4], bfup(wb[4]), b0_);
        b1_ = fmaf(sh[kb + 5], bfup(wb[5]), b1_);
        b2_ = fmaf(sh[kb + 6], bfup(wb[6]), b2_);
        b3_ = fmaf(sh[kb + 7], bfup(wb[7]), b3_);
    }
    A.abm[(size_t)r * 512 + c0] = (a0 + a1) + (a2 + a3);
    A.abm[(size_t)r * 512 + c1] = (b0_ + b1_) + (b2_ + b3_);
}

// ---------------- K_MID: 3 phases, 2 grid barriers, 8KB LDS (>=2 blocks/CU) ----------------
__global__ __launch_bounds__(256) void k_mid(MidArgs A) {
    __shared__ float sh[2048];
    int blk = blockIdx.x, tid = threadIdx.x;

    // ---- phase 1: LN(1024) + W1t(384) + wfg(1) + node jobs(64), grid-strided ----
    for (int j = blk; j < 1473; j += NBLK) {
        __syncthreads();   // protect LDS reuse across jobs
        if (j < 1024) {
            int row = j;
            const float* xr = A.x + (size_t)row * Hn;
            float v0 = xr[tid], v1 = xr[tid + 256], v2 = xr[tid + 512];
            float s = v0 + v1 + v2;
            float q = v0 * v0 + v1 * v1 + v2 * v2;
            float* sm = sh; float* qm = sh + 4;
            for (int o = 32; o > 0; o >>= 1) { s += __shfl_down(s, o); q += __shfl_down(q, o); }
            if ((tid & 63) == 0) { sm[tid >> 6] = s; qm[tid >> 6] = q; }
            __syncthreads();
            float S = sm[0] + sm[1] + sm[2] + sm[3];
            float Q = qm[0] + qm[1] + qm[2] + qm[3];
            float mean = S * (1.f / 768.f);
            float rstd = rsqrtf(Q * (1.f / 768.f) - mean * mean + 1e-5f);
            float* o0 = A.emb + (size_t)row * Hn;
            o0[tid]       = (v0 - mean) * rstd * A.g0[tid]       + A.b0[tid];
            o0[tid + 256] = (v1 - mean) * rstd * A.g0[tid + 256] + A.b0[tid + 256];
            o0[tid + 512] = (v2 - mean) * rstd * A.g0[tid + 512] + A.b0[tid + 512];
        } else if (j < 1408) {
            float (*tile)[33] = (float(*)[33])sh;
            int idx = j - 1024;
            int kt = idx % 24, nt = idx / 24;
            int k0 = kt * 32, n0 = nt * 32;
            int rowoff = (n0 < 256) ? 0 : 768;
            int col0 = n0 & 255;
            int r = tid >> 3, c = (tid & 7) * 4;
            float4 v = *(const float4*)(A.W1 + (size_t)(rowoff + k0 + r) * 256 + col0 + c);
            tile[r][c] = v.x; tile[r][c + 1] = v.y; tile[r][c + 2] = v.z; tile[r][c + 3] = v.w;
            __syncthreads();
            ushort4 o;
            o.x = f2bf(tile[c][r]); o.y = f2bf(tile[c + 1][r]);
            o.z = f2bf(tile[c + 2][r]); o.w = f2bf(tile[c + 3][r]);
            *(ushort4*)(A.w1t + (size_t)(n0 + r) * 768 + k0 + c) = o;
        } else if (j == 1408) {
#pragma unroll
            for (int u = 0; u < 2; ++u) {
                int e = tid + u * 256;
                int s = e >> 6, l = e & 63;
                int qq2 = l >> 4, nn2 = l & 15;
                short8 wv;
#pragma unroll
                for (int t = 0; t < 8; ++t) {
                    int k = s * 32 + qq2 * 8 + t;
                    float v = (nn2 < 6) ? A.Wc[k * 6 + nn2] : ((nn2 < 8) ? A.Wc1[k * 2 + (nn2 - 6)] : 0.f);
                    wv[t] = (short)f2bf(v);
                }
                *(short8*)(A.wfg + e * 8) = wv;
            }
            A.wfg[4096 + tid] = f2bf(A.g1[tid]);
            A.wfg[4352 + tid] = f2bf(A.b1[tid]);
        } else {
            node_job(A, j - 1409, tid, sh);
        }
    }

    // ---- barrier 1: all 512 arrive; only blocks <192 continue ----
    if (blk >= 192) { gbar2(A.bar, 64u, blk, tid, false); return; }
    gbar2(A.bar, 64u, blk, tid, true);

    // ---- phase 2 ----
    if (blk >= 64) {
        int j = blk - 64;   // 128 gemm-main jobs, 4 waves each
        gemm_wave(A.emb, A.w1t, A.abm, j * 4 + (tid >> 6), tid & 63);
        gbar2(A.bar + 160, 24u, blk, tid, false);
        return;
    }
    graph_chain(A, blk, tid, sh);
    gbar2(A.bar + 160, 24u, blk, tid, true);

    // ---- phase 3: fix dirtied abm rows ----
    gemm_fix(A, blk, tid, sh);
}

// ---------------- K11: fully fused LN-stats + GELU + MFMA-proj (unchanged) ----------------
__global__ __launch_bounds__(256) void k_hidden3(const float* __restrict__ abm,
                                                 const float* __restrict__ bl1,
                                                 const float* __restrict__ masks,
                                                 const unsigned short* __restrict__ wfg,
                                                 const float* __restrict__ bc,
                                                 const float* __restrict__ bc1,
                                                 float* __restrict__ out) {
    __shared__ unsigned short As[16][PITCH];
    __shared__ unsigned short Bs[16][PITCH];
    __shared__ unsigned short gsh[256], bsh[256];
    __shared__ short8 Wf[8][64];
    __shared__ float Ds[16][16];
    __shared__ float ms[16][16];
    __shared__ float sAs[16], qAs[16], sBs[16], qBs[16];
    int tid = threadIdx.x;
    int jt = blockIdx.x, it = blockIdx.y, b = blockIdx.z;
    int rowA = b * 256 + it * 16;
    int rowB = b * 256 + jt * 16;
    {
        int r = tid >> 4, sg = tid & 15;
        const float* Ar = abm + (size_t)(rowA + r) * 512 + sg * 16;
        const float* Br = abm + (size_t)(rowB + r) * 512 + 256 + sg * 16;
        const float* Lr = bl1 + sg * 16;
        float sa = 0.f, qa = 0.f, sb = 0.f, qb = 0.f;
        short8 va0, va1, vb0, vb1;
#pragma unroll
        for (int u = 0; u < 4; ++u) {
            float4 av = *(const float4*)(Ar + u * 4);
            float4 bv = *(const float4*)(Br + u * 4);
            float4 lv = *(const float4*)(Lr + u * 4);
            float aa[4] = {av.x, av.y, av.z, av.w};
            float bb[4] = {bv.x + lv.x, bv.y + lv.y, bv.z + lv.z, bv.w + lv.w};
#pragma unroll
            for (int e = 0; e < 4; ++e) {
                unsigned short ah = f2bf(aa[e]), bh = f2bf(bb[e]);
                float af = bfup(ah), bf2 = bfup(bh);
                sa += af; qa = fmaf(af, af, qa);
                sb += bf2; qb = fmaf(bf2, bf2, qb);
                int pos = u * 4 + e;
                if (pos < 8) { va0[pos] = (short)ah; vb0[pos] = (short)bh; }
                else         { va1[pos - 8] = (short)ah; vb1[pos - 8] = (short)bh; }
            }
        }
        *(short8*)&As[r][sg * 16]     = va0;
        *(short8*)&As[r][sg * 16 + 8] = va1;
        *(short8*)&Bs[r][sg * 16]     = vb0;
        *(short8*)&Bs[r][sg * 16 + 8] = vb1;
        for (int o = 8; o > 0; o >>= 1) {
            sa += __shfl_down(sa, o); qa += __shfl_down(qa, o);
            sb += __shfl_down(sb, o); qb += __shfl_down(qb, o);
        }
        if (sg == 0) { sAs[r] = sa; qAs[r] = qa; sBs[r] = sb; qBs[r] = qb; }
    }
#pragma unroll
    for (int u = 0; u < 2; ++u) {
        int e = tid + u * 256;
        ((short8*)Wf)[e] = *(const short8*)(wfg + e * 8);
    }
    gsh[tid] = wfg[4096 + tid];
    bsh[tid] = wfg[4352 + tid];
    {
        int di = tid >> 4, dj = tid & 15;
        ms[di][dj] = masks[((size_t)(b * 256 + it * 16 + di)) * 256 + jt * 16 + dj];
    }
    __syncthreads();
    if (tid < 64) {
        int m = tid & 15, q = tid >> 4;
        floatx4 acc = {0.f, 0.f, 0.f, 0.f};
#pragma unroll
        for (int s = 0; s < 8; ++s) {
            short8 a8 = *(const short8*)&As[m][s * 32 + q * 8];
            short8 b8 = *(const short8*)&Bs[m][s * 32 + q * 8];
            acc = __builtin_amdgcn_mfma_f32_16x16x32_bf16(a8, b8, acc, 0, 0, 0);
        }
#pragma unroll
        for (int rg = 0; rg < 4; ++rg) Ds[q * 4 + rg][m] = acc[rg];
    }
    __syncthreads();

    int lane = tid & 63, w = tid >> 6;
    int m = lane & 15, q = lane >> 4;
    int iA = w * 4 + (m & 3);
    int jB0 = m >> 2;
    int n = m;
    float bcs_l = (n < 6) ? bc[n] : ((n < 8) ? bc1[n - 6] : 0.f);
    const float inv256 = 1.f / 256.f;
    const float K1 = -1.5957691216f, K2 = -0.0713548163f;

    float rr4[4], cc4[4];
#pragma unroll
    for (int p = 0; p < 4; ++p) {
        int jB = p * 4 + jB0;
        float mu = (sAs[iA] + sBs[jB]) * inv256;
        float E2 = (qAs[iA] + 2.f * Ds[iA][jB] + qBs[jB]) * inv256;
        float r_ = rsqrtf(E2 - mu * mu + 1e-5f);
        rr4[p] = r_;
        cc4[p] = -mu * r_;
    }
    floatx4 acc0 = {0.f, 0.f, 0.f, 0.f};
    floatx4 acc1 = {0.f, 0.f, 0.f, 0.f};
    floatx4 acc2 = {0.f, 0.f, 0.f, 0.f};
    floatx4 acc3 = {0.f, 0.f, 0.f, 0.f};

#pragma unroll 2
    for (int s = 0; s < 8; ++s) {
        int ko = s * 32 + q * 8;
        short8 a8 = *(const short8*)&As[iA][ko];
        short8 g8 = *(const short8*)&gsh[ko];
        short8 v8 = *(const short8*)&bsh[ko];
        short8 wv = Wf[s][lane];
        float af[8], gf[8], vf[8];
#pragma unroll
        for (int t = 0; t < 8; ++t) { af[t] = bfup(a8[t]); gf[t] = bfup(g8[t]); vf[t] = bfup(v8[t]); }
#define PSTEP(P, ACC) do {                                                        \
        short8 b8 = *(const short8*)&Bs[P * 4 + jB0][ko];                         \
        float r_ = rr4[P], c_ = cc4[P];                                           \
        short8 yv;                                                                \
        _Pragma("unroll")                                                         \
        for (int t = 0; t < 8; ++t) {                                             \
            float x = fmaf(af[t] + bfup(b8[t]), r_, c_);                          \
            x = fmaf(x, gf[t], vf[t]);                                            \
            float mm = fmaf(x * x, K2, K1);                                       \
            float e = __expf(x * mm);                                             \
            float y = x * __builtin_amdgcn_rcpf(1.f + e);                         \
            union { float f; unsigned u; } cv; cv.f = y;                          \
            yv[t] = (short)((cv.u + 0x8000u) >> 16);                              \
        }                                                                         \
        ACC = __builtin_amdgcn_mfma_f32_16x16x32_bf16(yv, wv, ACC, 0, 0, 0);      \
    } while (0)
        PSTEP(0, acc0);
        PSTEP(1, acc1);
        PSTEP(2, acc2);
        PSTEP(3, acc3);
#undef PSTEP
    }

    if (n < 8) {
#pragma unroll
        for (int rg = 0; rg < 4; ++rg) {
            int mp = q * 4 + rg;
            int il = w * 4 + (mp & 3);
            int base_j = mp >> 2;
            size_t rowbase = ((size_t)(b * 256 + it * 16 + il)) * 256 + jt * 16;
            {
                int jl = 0 * 4 + base_j;
                out[(rowbase + jl) * 8 + n] = (acc0[rg] + bcs_l) * ms[il][jl];
            }
            {
                int jl = 1 * 4 + base_j;
                out[(rowbase + jl) * 8 + n] = (acc1[rg] + bcs_l) * ms[il][jl];
            }
            {
                int jl = 2 * 4 + base_j;
                out[(rowbase + jl) * 8 + n] = (acc2[rg] + bcs_l) * ms[il][jl];
            }
            {
                int jl = 3 * 4 + base_j;
                out[(rowbase + jl) * 8 + n] = (acc3[rg] + bcs_l) * ms[il][jl];
            }
        }
    }
}

// ---------------- launch ----------------
extern "C" void kernel_launch(void* const* d_in, const int* in_sizes, int n_in,
                              void* d_out, int out_size, void* d_ws, size_t ws_size,
                              hipStream_t stream) {
    (void)in_sizes; (void)n_in; (void)out_size; (void)ws_size;
    const float* emb_in = (const float*)d_in[0];
    const float* masks  = (const float*)d_in[1];
    const int* ast = (const int*)d_in[2];
    const int* aed = (const int*)d_in[3];
    const int* ost = (const int*)d_in[4];
    const int* oed = (const int*)d_in[5];
    const int* sid = (const int*)d_in[6];
    const float* E    = (const float*)d_in[7];
    const float* Wtp  = (const float*)d_in[8];
    const float* btp  = (const float*)d_in[9];
    const float* Wat  = (const float*)d_in[10];
    const float* bat  = (const float*)d_in[11];
    const float* Wg   = (const float*)d_in[12];
    const float* bg   = (const float*)d_in[13];
    const float* g0   = (const float*)d_in[14];
    const float* b0   = (const float*)d_in[15];
    const float* W1   = (const float*)d_in[16];
    const float* bl1  = (const float*)d_in[17];
    const float* g1   = (const float*)d_in[18];
    const float* b1   = (const float*)d_in[19];
    const float* Wc   = (const float*)d_in[20];
    const float* bc   = (const float*)d_in[21];
    const float* Wc1  = (const float*)d_in[22];
    const float* bc1  = (const float*)d_in[23];
    float* outp = (float*)d_out;

    // ---- workspace layout (floats; FIXED round-6 bug: nf is 64x768=49152, was 12288) ----
    float* fw = (float*)d_ws;
    float* emb = fw;                                       // [0, 786432)        1024x768
    float* nf  = fw + 786432;                              // [786432, 835584)   64x768
    float* hedge = fw + 835584;                            // [835584, 835588)   pad to 835600
    float* abm = fw + 835600;                              // [835600, 1359888)  1024x512
    unsigned short* w1t = (unsigned short*)(fw + 1359888); // 393216 us = 196608 fl -> 1556496
    unsigned short* wfg = (unsigned short*)(fw + 1556496); // 4608 us = 2304 fl  -> 1558800
    unsigned* bar = (unsigned*)(fw + 1558800);             // 320 u32 (2 barriers x 160)

    hipMemsetAsync((void*)bar, 0, 1280, stream);

    MidArgs ma;
    ma.x = emb_in; ma.g0 = g0; ma.b0 = b0;
    ma.emb = emb;
    ma.W1 = W1; ma.w1t = w1t;
    ma.Wc = Wc; ma.Wc1 = Wc1; ma.g1 = g1; ma.b1 = b1;
    ma.wfg = wfg;
    ma.ast = ast; ma.aed = aed; ma.ost = ost; ma.oed = oed; ma.sid = sid;
    ma.nf = nf; ma.hedge = hedge;
    ma.Wtp = Wtp; ma.btp = btp;
    ma.E = E; ma.Wat = Wat; ma.bat = bat;
    ma.Wg = Wg; ma.bg = bg;
    ma.abm = abm;
    ma.bar = bar;

    k_mid<<<NBLK, 256, 0, stream>>>(ma);

    dim3 g6(16, 16, 4);
    k_hidden3<<<g6, 256, 0, stream>>>(abm, bl1, masks, wfg, bc, bc1, outp);
}

// Round 8
// 268.313 us; speedup vs baseline: 2.7872x; 2.7872x over previous
//
#include <hip/hip_runtime.h>

// ---------------- helpers ----------------
__device__ __forceinline__ unsigned short f2bf(float f) {
    union { float f; unsigned u; } v; v.f = f;
    unsigned u = v.u;
    unsigned r = (u + 0x7fffu + ((u >> 16) & 1u)) >> 16;
    return (unsigned short)r;
}
__device__ __forceinline__ float bfup(int x) {
    union { unsigned u; float f; } v; v.u = ((unsigned)(unsigned short)x) << 16; return v.f;
}

typedef __attribute__((ext_vector_type(8))) short short8;
typedef __attribute__((ext_vector_type(4))) float floatx4;

// dims
#define Bn 4
#define Ln 256
#define Hn 768
#define Tn 16
#define PITCH 288   // bf16 pitch: 144 dwords, 144%32=16 -> 2-way (free) LDS aliasing
#define PN 784      // k_graph nf LDS pitch: rows alternate bank offset 0/16 -> 2-way (free)

// ---------------- K1: LN (0..1023) + W1t (1024..1407) + Wf table (1408) + spans (1409..1472)
__global__ __launch_bounds__(256) void k_pre(const float* __restrict__ x,
                                             const float* __restrict__ g,
                                             const float* __restrict__ be,
                                             float* __restrict__ out,
                                             const float* __restrict__ W1,
                                             unsigned short* __restrict__ w1t,
                                             const float* __restrict__ Wc,
                                             const float* __restrict__ Wc1,
                                             const float* __restrict__ g1,
                                             const float* __restrict__ b1,
                                             unsigned short* __restrict__ wfg,
                                             const int* __restrict__ ast_, const int* __restrict__ aed_,
                                             const int* __restrict__ ost_, const int* __restrict__ oed_,
                                             const int* __restrict__ sid_,
                                             float* __restrict__ xv,
                                             float* __restrict__ nf,
                                             float* __restrict__ hedge) {
    int bid = blockIdx.x, tid = threadIdx.x;
    if (bid < 1024) {
        int row = bid;
        const float* xr = x + (size_t)row * Hn;
        float v0 = xr[tid], v1 = xr[tid + 256], v2 = xr[tid + 512];
        float s = v0 + v1 + v2;
        float q = v0 * v0 + v1 * v1 + v2 * v2;
        __shared__ float sm[4], qm[4];
        for (int o = 32; o > 0; o >>= 1) { s += __shfl_down(s, o); q += __shfl_down(q, o); }
        if ((tid & 63) == 0) { sm[tid >> 6] = s; qm[tid >> 6] = q; }
        __syncthreads();
        float S = sm[0] + sm[1] + sm[2] + sm[3];
        float Q = qm[0] + qm[1] + qm[2] + qm[3];
        float mean = S * (1.f / 768.f);
        float rstd = rsqrtf(Q * (1.f / 768.f) - mean * mean + 1e-5f);
        float* o0 = out + (size_t)row * Hn;
        o0[tid]       = (v0 - mean) * rstd * g[tid]       + be[tid];
        o0[tid + 256] = (v1 - mean) * rstd * g[tid + 256] + be[tid + 256];
        o0[tid + 512] = (v2 - mean) * rstd * g[tid + 512] + be[tid + 512];
    } else if (bid < 1408) {
        __shared__ float tile[32][33];
        int idx = bid - 1024;
        int kt = idx % 24, nt = idx / 24;
        int k0 = kt * 32, n0 = nt * 32;
        int rowoff = (n0 < 256) ? 0 : 768;
        int col0 = n0 & 255;
        int r = tid >> 3, c = (tid & 7) * 4;
        float4 v = *(const float4*)(W1 + (size_t)(rowoff + k0 + r) * 256 + col0 + c);
        tile[r][c] = v.x; tile[r][c + 1] = v.y; tile[r][c + 2] = v.z; tile[r][c + 3] = v.w;
        __syncthreads();
        ushort4 o;
        o.x = f2bf(tile[c][r]); o.y = f2bf(tile[c + 1][r]);
        o.z = f2bf(tile[c + 2][r]); o.w = f2bf(tile[c + 3][r]);
        *(ushort4*)(w1t + (size_t)(n0 + r) * 768 + k0 + c) = o;
    } else if (bid == 1408) {
        // Wf table + bf16 gamma/beta
#pragma unroll
        for (int u = 0; u < 2; ++u) {
            int e = tid + u * 256;
            int s = e >> 6, l = e & 63;
            int qq2 = l >> 4, nn2 = l & 15;
            short8 wv;
#pragma unroll
            for (int t = 0; t < 8; ++t) {
                int k = s * 32 + qq2 * 8 + t;
                float v = (nn2 < 6) ? Wc[k * 6 + nn2] : ((nn2 < 8) ? Wc1[k * 2 + (nn2 - 6)] : 0.f);
                wv[t] = (short)f2bf(v);
            }
            *(short8*)(wfg + e * 8) = wv;
        }
        wfg[4096 + tid] = f2bf(g1[tid]);
        wfg[4352 + tid] = f2bf(b1[tid]);
        if (tid < 4) hedge[tid] = 0.f;   // zero-init: k_graph ORs into this via atomicAdd
    } else {
        // spans with own LN stats (reads pristine emb_in = x)
        __shared__ float rstdA[3], rstdO[3], cc[2];
        __shared__ float sred[4], qred[4];
        int n = bid - 1409, b = n >> 4;
        int ast = ast_[n], aed = aed_[n], ost = ost_[n], oed = oed_[n], sid = sid_[n];
        int na = aed - ast + 1, no2 = oed - ost + 1;
        if (tid == 0) { cc[0] = 0.f; cc[1] = 0.f; }
        __syncthreads();
        for (int slot = 0; slot < 6; ++slot) {
            int isA = slot < 3;
            int off = isA ? slot : slot - 3;
            int cnt = isA ? na : no2;
            int row = (isA ? ast : ost) + off;
            if (off < cnt) {
                const float* xr = x + (size_t)(b * 256 + row) * Hn;
                float v0 = xr[tid], v1 = xr[tid + 256], v2 = xr[tid + 512];
                float s = v0 + v1 + v2;
                float q = v0 * v0 + v1 * v1 + v2 * v2;
                for (int o = 32; o > 0; o >>= 1) { s += __shfl_down(s, o); q += __shfl_down(q, o); }
                if ((tid & 63) == 0) { sred[tid >> 6] = s; qred[tid >> 6] = q; }
            }
            __syncthreads();
            if (off < cnt && tid == 0) {
                float S = sred[0] + sred[1] + sred[2] + sred[3];
                float Q = qred[0] + qred[1] + qred[2] + qred[3];
                float mean = S * (1.f / 768.f);
                float rstd = rsqrtf(Q * (1.f / 768.f) - mean * mean + 1e-5f);
                if (isA) { rstdA[off] = rstd; cc[0] += mean * rstd; }
                else     { rstdO[off] = rstd; cc[1] += mean * rstd; }
            }
            __syncthreads();
        }
        float ai = 1.f / (float)na, oi = 1.f / (float)no2;
        float cA = cc[0] * ai, cO = cc[1] * oi;
        float* xrr = xv + (size_t)n * 1568;
        const float* eb = x + (size_t)b * Ln * Hn;
        for (int r = tid; r < 1568; r += 256) {
            float v;
            if (r < 768) {
                float sa = 0.f;
                for (int l = 0; l < na; ++l) sa = fmaf(eb[(ast + l) * Hn + r], rstdA[l], sa);
                v = fmaf(g[r], sa * ai - cA, be[r]);
            } else if (r < 1536) {
                int h = r - 768;
                float so = 0.f;
                for (int l = 0; l < no2; ++l) so = fmaf(eb[(ost + l) * Hn + h], rstdO[l], so);
                v = fmaf(g[h], so * oi - cO, be[h]);
            } else if (r < 1539) {
                v = (sid - 2 == r - 1536) ? 1.f : 0.f;
            } else {
                v = 0.f;
            }
            xrr[r] = v;
        }
        float* nr = nf + (size_t)n * Hn;
        nr[tid] = 0.f; nr[tid + 256] = 0.f; nr[tid + 512] = 0.f;
    }
}

// ---------------- split-K skinny GEMM: C[M x 768] += A[M x Kpad] @ B[Kb x 768]
__global__ __launch_bounds__(256) void k_skinny(const float* __restrict__ A,
                                                const float* __restrict__ B,
                                                const float* __restrict__ bias,
                                                float* __restrict__ C,
                                                int Kpad, int Kb, int Kc) {
    __shared__ float At[32][33], Bt[32][33];
    int tid = threadIdx.x;
    int n0 = blockIdx.x * 32, m0 = blockIdx.y * 32, z = blockIdx.z;
    int kbeg = z * Kc;
    int kend = kbeg + Kc; if (kend > Kpad) kend = Kpad;
    int lr = tid >> 3, lc = (tid & 7) * 4;
    int tm = tid >> 3, tn4 = (tid & 7) * 4;
    float acc0 = 0.f, acc1 = 0.f, acc2 = 0.f, acc3 = 0.f;
    for (int k0 = kbeg; k0 < kend; k0 += 32) {
        float4 av = *(const float4*)(A + (size_t)(m0 + lr) * Kpad + k0 + lc);
        At[lr][lc] = av.x; At[lr][lc + 1] = av.y; At[lr][lc + 2] = av.z; At[lr][lc + 3] = av.w;
        int gk = k0 + lr;
        float4 bv = {0.f, 0.f, 0.f, 0.f};
        if (gk < Kb) bv = *(const float4*)(B + (size_t)gk * 768 + n0 + lc);
        Bt[lr][lc] = bv.x; Bt[lr][lc + 1] = bv.y; Bt[lr][lc + 2] = bv.z; Bt[lr][lc + 3] = bv.w;
        __syncthreads();
#pragma unroll
        for (int k = 0; k < 32; ++k) {
            float a = At[tm][k];
            acc0 = fmaf(a, Bt[k][tn4], acc0);
            acc1 = fmaf(a, Bt[k][tn4 + 1], acc1);
            acc2 = fmaf(a, Bt[k][tn4 + 2], acc2);
            acc3 = fmaf(a, Bt[k][tn4 + 3], acc3);
        }
        __syncthreads();
    }
    if (z == 0) {
        acc0 += bias[n0 + tn4];
        acc1 += bias[n0 + tn4 + 1];
        acc2 += bias[n0 + tn4 + 2];
        acc3 += bias[n0 + tn4 + 3];
    }
    float* dst = C + (size_t)(m0 + tm) * 768 + n0 + tn4;
    atomicAdd(&dst[0], acc0);
    atomicAdd(&dst[1], acc1);
    atomicAdd(&dst[2], acc2);
    atomicAdd(&dst[3], acc3);
}

// ---------------- K4: graph attention + aggregation (round-1 verified) ----------------
__global__ __launch_bounds__(256) void k_graph(const float* __restrict__ nf,
                                               const int* __restrict__ ast_, const int* __restrict__ aed_,
                                               const int* __restrict__ ost_, const int* __restrict__ oed_,
                                               const float* __restrict__ E,
                                               const float* __restrict__ Wat,
                                               const float* __restrict__ bat,
                                               int* __restrict__ hasin, float* __restrict__ hasedge,
                                               float* __restrict__ agg, float* __restrict__ raw) {
    int n = blockIdx.x, b = n >> 4, t = n & 15, tid = threadIdx.x;
    __shared__ float nfs[16][PN];
    __shared__ float dotS[16], n2S[16], qS[16];
    __shared__ float pT_s, rr0_s, rr1_s;
    __shared__ int ast[16], aed[16], ost[16], oed[16];
    __shared__ float wss[16];
    __shared__ float aes0, aes1;
    const float* nfb = nf + (size_t)b * 16 * Hn;
    if (tid < 16) {
        int m = b * 16 + tid;
        ast[tid] = ast_[m]; aed[tid] = aed_[m];
        ost[tid] = ost_[m]; oed[tid] = oed_[m];
    }
    // ---- phase A: group s = tid>>4 owns source node s ----
    int s = tid >> 4, l = tid & 15;
    const float* vs = nfb + (size_t)s * Hn;
    const float* vt = nfb + (size_t)t * Hn;
    const float* er = E + ((s == 2) ? 768 : 0);
    float d = 0.f, n2 = 0.f, qq = 0.f, pp = 0.f, rr = 0.f;
#pragma unroll 4
    for (int h = l; h < 768; h += 16) {
        float v = vs[h];
        float tv = vt[h];
        nfs[s][h] = v;
        d  = fmaf(tv, v, d);
        n2 = fmaf(v, v, n2);
        float lv = v > 0.f ? v : 0.2f * v;
        qq = fmaf(lv, Wat[768 + h], qq);
        if (s == 0) { float lt = tv > 0.f ? tv : 0.2f * tv; pp = fmaf(lt, Wat[h], pp); }
        if (s == 1 || s == 2) { float ev = er[h]; float le = ev > 0.f ? ev : 0.2f * ev; rr = fmaf(le, Wat[1536 + h], rr); }
    }
    for (int o = 8; o > 0; o >>= 1) {
        d  += __shfl_down(d, o);  n2 += __shfl_down(n2, o);
        qq += __shfl_down(qq, o); pp += __shfl_down(pp, o);
        rr += __shfl_down(rr, o);
    }
    if (l == 0) {
        dotS[s] = d; n2S[s] = n2; qS[s] = qq;
        if (s == 0) pT_s = pp;
        if (s == 1) rr0_s = rr;
        if (s == 2) rr1_s = rr;
    }
    __syncthreads();
    // ---- phase B: wave 0, 32-entry masked softmax, lane-parallel ----
    if (tid < 64) {
        int ss = tid >> 1, e = tid & 1;
        bool valid = tid < 32;
        int ssc = ss & 15;
        float nt = sqrtf(n2S[t]);
        float ns = sqrtf(n2S[ssc]);
        float sim = dotS[ssc] / (fmaxf(nt, 1e-8f) * fmaxf(ns, 1e-8f));
        bool ok = valid && (sim > 0.f) && (ssc != t);
        bool edge;
        if (e == 0) edge = ok && (ast[t] == ast[ssc]) && (aed[t] == aed[ssc]);
        else        edge = ok && (ost[t] == ost[ssc]) && (oed[t] == oed[ssc]);
        float sc = edge ? (pT_s + qS[ssc] + (e ? rr1_s : rr0_s) + bat[0]) : -1e9f;
        float mx = sc;
        for (int o = 16; o > 0; o >>= 1) mx = fmaxf(mx, __shfl_xor(mx, o));
        float ex = __expf(sc - mx);
        float sum = ex;
        for (int o = 16; o > 0; o >>= 1) sum += __shfl_xor(sum, o);
        float w = ex / sum;
        float wtot = w + __shfl_xor(w, 1);
        if (valid && e == 0) wss[ss] = wtot;
        float a0 = (valid && e == 0) ? w : 0.f;
        float a1 = (valid && e == 1) ? w : 0.f;
        for (int o = 16; o > 0; o >>= 1) { a0 += __shfl_xor(a0, o); a1 += __shfl_xor(a1, o); }
        unsigned long long bal = __ballot(edge);
        if (tid == 0) {
            aes0 = a0; aes1 = a1;
            int hi = (bal != 0ull) ? 1 : 0;
            hasin[n] = hi;
            if (hi) atomicAdd(&hasedge[b], 1.f);
        }
    }
    __syncthreads();
    // ---- phase C: aggregation row t (768 wide) ----
    float ae0 = aes0, ae1 = aes1;
    float* ag = agg + (size_t)n * 1536;
    float* rw = raw + (size_t)n * Hn;
    for (int f = tid; f < 768; f += 256) {
        float acc = 0.f;
#pragma unroll
        for (int s16 = 0; s16 < 16; ++s16) acc = fmaf(wss[s16], nfs[s16][f], acc);
        ag[f] = acc;
        ag[768 + f] = ae0 * E[f] + ae1 * E[768 + f];
        rw[f] = 0.f;
    }
}

// ---------------- K7: MFMA GEMM  abm[1024][512] = bf16(emb + scatter) @ w1t^T ----------------
// Scatter folded in: centers = (ast+ost)>>1 <= 11 < 16, so only the Af0 row-set of
// blocks with m0%256==0 is affected. Each lane adds its matching nodes' (relu'd raw
// | nf) contribution in fp32 BEFORE bf16 pack — bit-identical to the old
// scatter+read path modulo fp add order. emb itself stays pre-scatter (dead after).
__global__ __launch_bounds__(64) void k_gemm(const float* __restrict__ emb,
                                             const unsigned short* __restrict__ w1t,
                                             float* __restrict__ abm,
                                             const float* __restrict__ raw,
                                             const float* __restrict__ nf,
                                             const int* __restrict__ hasin,
                                             const float* __restrict__ hasedge,
                                             const int* __restrict__ ast_,
                                             const int* __restrict__ ost_) {
    int wid = blockIdx.x;                 // 512 waves
    int m0 = (wid >> 4) * 32;
    int n0 = (wid & 15) * 32;
    int lane = threadIdx.x;
    int r = lane & 15, g = lane >> 4;
    // per-lane scatter-match masks (only first 32-row tile of each batch can match)
    unsigned mrel = 0u, mnf = 0u;
    int b16 = (m0 >> 8) * 16;
    if (((wid >> 4) & 7) == 0 && hasedge[m0 >> 8] != 0.f) {
#pragma unroll
        for (int t = 0; t < 16; ++t) {
            int nn = b16 + t;
            int c = (ast_[nn] + ost_[nn]) >> 1;
            if (c == r) { if (hasin[nn]) mrel |= 1u << t; else mnf |= 1u << t; }
        }
    }
    const float* Af0 = emb + (size_t)(m0 + r) * 768 + g * 8;
    const float* Af1 = emb + (size_t)(m0 + 16 + r) * 768 + g * 8;
    const short8* Bp0 = (const short8*)(w1t + (size_t)(n0 + r) * 768 + g * 8);
    const short8* Bp1 = (const short8*)(w1t + (size_t)(n0 + 16 + r) * 768 + g * 8);
    floatx4 acc00 = {0.f, 0.f, 0.f, 0.f}, acc01 = {0.f, 0.f, 0.f, 0.f};
    floatx4 acc10 = {0.f, 0.f, 0.f, 0.f}, acc11 = {0.f, 0.f, 0.f, 0.f};
#pragma unroll 4
    for (int ks = 0; ks < 768; ks += 32) {
        float4 x0 = *(const float4*)(Af0 + ks);
        float4 x1 = *(const float4*)(Af0 + ks + 4);
        float4 y0 = *(const float4*)(Af1 + ks);
        float4 y1 = *(const float4*)(Af1 + ks + 4);
        // scatter contributions for row m0+r (Af0 half only)
        unsigned mm = mrel;
        while (mm) {
            int t = __builtin_ctz(mm); mm &= mm - 1u;
            const float* sp = raw + (size_t)(b16 + t) * 768 + g * 8 + ks;
            float4 s0 = *(const float4*)sp;
            float4 s1 = *(const float4*)(sp + 4);
            x0.x += fmaxf(s0.x, 0.f); x0.y += fmaxf(s0.y, 0.f);
            x0.z += fmaxf(s0.z, 0.f); x0.w += fmaxf(s0.w, 0.f);
            x1.x += fmaxf(s1.x, 0.f); x1.y += fmaxf(s1.y, 0.f);
            x1.z += fmaxf(s1.z, 0.f); x1.w += fmaxf(s1.w, 0.f);
        }
        mm = mnf;
        while (mm) {
            int t = __builtin_ctz(mm); mm &= mm - 1u;
            const float* sp = nf + (size_t)(b16 + t) * 768 + g * 8 + ks;
            float4 s0 = *(const float4*)sp;
            float4 s1 = *(const float4*)(sp + 4);
            x0.x += s0.x; x0.y += s0.y; x0.z += s0.z; x0.w += s0.w;
            x1.x += s1.x; x1.y += s1.y; x1.z += s1.z; x1.w += s1.w;
        }
        short8 a0, a1;
        union { float f; unsigned u; } cv;
#define PK(dst, idx, val) { cv.f = (val); dst[idx] = (short)((cv.u + 0x8000u) >> 16); }
        PK(a0, 0, x0.x) PK(a0, 1, x0.y) PK(a0, 2, x0.z) PK(a0, 3, x0.w)
        PK(a0, 4, x1.x) PK(a0, 5, x1.y) PK(a0, 6, x1.z) PK(a0, 7, x1.w)
        PK(a1, 0, y0.x) PK(a1, 1, y0.y) PK(a1, 2, y0.z) PK(a1, 3, y0.w)
        PK(a1, 4, y1.x) PK(a1, 5, y1.y) PK(a1, 6, y1.z) PK(a1, 7, y1.w)
#undef PK
        short8 b0 = Bp0[ks >> 3];
        short8 b1 = Bp1[ks >> 3];
        acc00 = __builtin_amdgcn_mfma_f32_16x16x32_bf16(a0, b0, acc00, 0, 0, 0);
        acc01 = __builtin_amdgcn_mfma_f32_16x16x32_bf16(a0, b1, acc01, 0, 0, 0);
        acc10 = __builtin_amdgcn_mfma_f32_16x16x32_bf16(a1, b0, acc10, 0, 0, 0);
        acc11 = __builtin_amdgcn_mfma_f32_16x16x32_bf16(a1, b1, acc11, 0, 0, 0);
    }
#pragma unroll
    for (int t = 0; t < 4; ++t) {
        int row = g * 4 + t;
        abm[(size_t)(m0 + row) * 512 + n0 + r]           = acc00[t];
        abm[(size_t)(m0 + row) * 512 + n0 + 16 + r]      = acc01[t];
        abm[(size_t)(m0 + 16 + row) * 512 + n0 + r]      = acc10[t];
        abm[(size_t)(m0 + 16 + row) * 512 + n0 + 16 + r] = acc11[t];
    }
}

// ---------------- K11: fully fused LN-stats + GELU + MFMA-proj (unchanged) ----------------
__global__ __launch_bounds__(256) void k_hidden3(const float* __restrict__ abm,
                                                 const float* __restrict__ bl1,
                                                 const float* __restrict__ masks,
                                                 const unsigned short* __restrict__ wfg,
                                                 const float* __restrict__ bc,
                                                 const float* __restrict__ bc1,
                                                 float* __restrict__ out) {
    __shared__ unsigned short As[16][PITCH];
    __shared__ unsigned short Bs[16][PITCH];
    __shared__ unsigned short gsh[256], bsh[256];
    __shared__ short8 Wf[8][64];
    __shared__ float Ds[16][16];
    __shared__ float ms[16][16];
    __shared__ float sAs[16], qAs[16], sBs[16], qBs[16];
    int tid = threadIdx.x;
    int jt = blockIdx.x, it = blockIdx.y, b = blockIdx.z;
    int rowA = b * 256 + it * 16;
    int rowB = b * 256 + jt * 16;
    {
        int r = tid >> 4, sg = tid & 15;
        const float* Ar = abm + (size_t)(rowA + r) * 512 + sg * 16;
        const float* Br = abm + (size_t)(rowB + r) * 512 + 256 + sg * 16;
        const float* Lr = bl1 + sg * 16;
        float sa = 0.f, qa = 0.f, sb = 0.f, qb = 0.f;
        short8 va0, va1, vb0, vb1;
#pragma unroll
        for (int u = 0; u < 4; ++u) {
            float4 av = *(const float4*)(Ar + u * 4);
            float4 bv = *(const float4*)(Br + u * 4);
            float4 lv = *(const float4*)(Lr + u * 4);
            float aa[4] = {av.x, av.y, av.z, av.w};
            float bb[4] = {bv.x + lv.x, bv.y + lv.y, bv.z + lv.z, bv.w + lv.w};
#pragma unroll
            for (int e = 0; e < 4; ++e) {
                unsigned short ah = f2bf(aa[e]), bh = f2bf(bb[e]);
                float af = bfup(ah), bf2 = bfup(bh);
                sa += af; qa = fmaf(af, af, qa);
                sb += bf2; qb = fmaf(bf2, bf2, qb);
                int pos = u * 4 + e;
                if (pos < 8) { va0[pos] = (short)ah; vb0[pos] = (short)bh; }
                else         { va1[pos - 8] = (short)ah; vb1[pos - 8] = (short)bh; }
            }
        }
        *(short8*)&As[r][sg * 16]     = va0;
        *(short8*)&As[r][sg * 16 + 8] = va1;
        *(short8*)&Bs[r][sg * 16]     = vb0;
        *(short8*)&Bs[r][sg * 16 + 8] = vb1;
        for (int o = 8; o > 0; o >>= 1) {
            sa += __shfl_down(sa, o); qa += __shfl_down(qa, o);
            sb += __shfl_down(sb, o); qb += __shfl_down(qb, o);
        }
        if (sg == 0) { sAs[r] = sa; qAs[r] = qa; sBs[r] = sb; qBs[r] = qb; }
    }
#pragma unroll
    for (int u = 0; u < 2; ++u) {
        int e = tid + u * 256;
        ((short8*)Wf)[e] = *(const short8*)(wfg + e * 8);
    }
    gsh[tid] = wfg[4096 + tid];
    bsh[tid] = wfg[4352 + tid];
    {
        int di = tid >> 4, dj = tid & 15;
        ms[di][dj] = masks[((size_t)(b * 256 + it * 16 + di)) * 256 + jt * 16 + dj];
    }
    __syncthreads();
    if (tid < 64) {
        int m = tid & 15, q = tid >> 4;
        floatx4 acc = {0.f, 0.f, 0.f, 0.f};
#pragma unroll
        for (int s = 0; s < 8; ++s) {
            short8 a8 = *(const short8*)&As[m][s * 32 + q * 8];
            short8 b8 = *(const short8*)&Bs[m][s * 32 + q * 8];
            acc = __builtin_amdgcn_mfma_f32_16x16x32_bf16(a8, b8, acc, 0, 0, 0);
        }
#pragma unroll
        for (int rg = 0; rg < 4; ++rg) Ds[q * 4 + rg][m] = acc[rg];
    }
    __syncthreads();

    int lane = tid & 63, w = tid >> 6;
    int m = lane & 15, q = lane >> 4;
    int iA = w * 4 + (m & 3);
    int jB0 = m >> 2;
    int n = m;
    float bcs_l = (n < 6) ? bc[n] : ((n < 8) ? bc1[n - 6] : 0.f);
    const float inv256 = 1.f / 256.f;
    const float K1 = -1.5957691216f, K2 = -0.0713548163f;

    float rr4[4], cc4[4];
#pragma unroll
    for (int p = 0; p < 4; ++p) {
        int jB = p * 4 + jB0;
        float mu = (sAs[iA] + sBs[jB]) * inv256;
        float E2 = (qAs[iA] + 2.f * Ds[iA][jB] + qBs[jB]) * inv256;
        float r_ = rsqrtf(E2 - mu * mu + 1e-5f);
        rr4[p] = r_;
        cc4[p] = -mu * r_;
    }
    floatx4 acc0 = {0.f, 0.f, 0.f, 0.f};
    floatx4 acc1 = {0.f, 0.f, 0.f, 0.f};
    floatx4 acc2 = {0.f, 0.f, 0.f, 0.f};
    floatx4 acc3 = {0.f, 0.f, 0.f, 0.f};

#pragma unroll 2
    for (int s = 0; s < 8; ++s) {
        int ko = s * 32 + q * 8;
        short8 a8 = *(const short8*)&As[iA][ko];
        short8 g8 = *(const short8*)&gsh[ko];
        short8 v8 = *(const short8*)&bsh[ko];
        short8 wv = Wf[s][lane];
        float af[8], gf[8], vf[8];
#pragma unroll
        for (int t = 0; t < 8; ++t) { af[t] = bfup(a8[t]); gf[t] = bfup(g8[t]); vf[t] = bfup(v8[t]); }
#define PSTEP(P, ACC) do {                                                        \
        short8 b8 = *(const short8*)&Bs[P * 4 + jB0][ko];                         \
        float r_ = rr4[P], c_ = cc4[P];                                           \
        short8 yv;                                                                \
        _Pragma("unroll")                                                         \
        for (int t = 0; t < 8; ++t) {                                             \
            float x = fmaf(af[t] + bfup(b8[t]), r_, c_);                          \
            x = fmaf(x, gf[t], vf[t]);                                            \
            float mm = fmaf(x * x, K2, K1);                                       \
            float e = __expf(x * mm);                                             \
            float y = x * __builtin_amdgcn_rcpf(1.f + e);                         \
            union { float f; unsigned u; } cv; cv.f = y;                          \
            yv[t] = (short)((cv.u + 0x8000u) >> 16);                              \
        }                                                                         \
        ACC = __builtin_amdgcn_mfma_f32_16x16x32_bf16(yv, wv, ACC, 0, 0, 0);      \
    } while (0)
        PSTEP(0, acc0);
        PSTEP(1, acc1);
        PSTEP(2, acc2);
        PSTEP(3, acc3);
#undef PSTEP
    }

    if (n < 8) {
#pragma unroll
        for (int rg = 0; rg < 4; ++rg) {
            int mp = q * 4 + rg;
            int il = w * 4 + (mp & 3);
            int base_j = mp >> 2;
            size_t rowbase = ((size_t)(b * 256 + it * 16 + il)) * 256 + jt * 16;
            {
                int jl = 0 * 4 + base_j;
                out[(rowbase + jl) * 8 + n] = (acc0[rg] + bcs_l) * ms[il][jl];
            }
            {
                int jl = 1 * 4 + base_j;
                out[(rowbase + jl) * 8 + n] = (acc1[rg] + bcs_l) * ms[il][jl];
            }
            {
                int jl = 2 * 4 + base_j;
                out[(rowbase + jl) * 8 + n] = (acc2[rg] + bcs_l) * ms[il][jl];
            }
            {
                int jl = 3 * 4 + base_j;
                out[(rowbase + jl) * 8 + n] = (acc3[rg] + bcs_l) * ms[il][jl];
            }
        }
    }
}

// ---------------- launch ----------------
extern "C" void kernel_launch(void* const* d_in, const int* in_sizes, int n_in,
                              void* d_out, int out_size, void* d_ws, size_t ws_size,
                              hipStream_t stream) {
    (void)in_sizes; (void)n_in; (void)out_size; (void)ws_size;
    const float* emb_in = (const float*)d_in[0];
    const float* masks  = (const float*)d_in[1];
    const int* ast = (const int*)d_in[2];
    const int* aed = (const int*)d_in[3];
    const int* ost = (const int*)d_in[4];
    const int* oed = (const int*)d_in[5];
    const int* sid = (const int*)d_in[6];
    const float* E    = (const float*)d_in[7];
    const float* Wtp  = (const float*)d_in[8];
    const float* btp  = (const float*)d_in[9];
    const float* Wat  = (const float*)d_in[10];
    const float* bat  = (const float*)d_in[11];
    const float* Wg   = (const float*)d_in[12];
    const float* bg   = (const float*)d_in[13];
    const float* g0   = (const float*)d_in[14];
    const float* b0   = (const float*)d_in[15];
    const float* W1   = (const float*)d_in[16];
    const float* bl1  = (const float*)d_in[17];
    const float* g1   = (const float*)d_in[18];
    const float* b1   = (const float*)d_in[19];
    const float* Wc   = (const float*)d_in[20];
    const float* bc   = (const float*)d_in[21];
    const float* Wc1  = (const float*)d_in[22];
    const float* bc1  = (const float*)d_in[23];
    float* outp = (float*)d_out;

    float* fw = (float*)d_ws;
    float* emb = fw;                                   // 786432
    float* nf  = fw + 786432;                          // 49152 -> 835584
    int*   hasin = (int*)(fw + 835584);                // 64
    float* hasedge = fw + 835648;                      // 4 (pad to 835712)
    float* xv  = fw + 835712;                          // 100352 -> 936064
    float* agg = fw + 936064;                          // 98304  -> 1034368
    float* raw = fw + 1034368;                         // 49152  -> 1083520
    float* abm = fw + 1083520;                         // 524288 -> 1607808
    unsigned short* w1t = (unsigned short*)(fw + 1607808); // 393216 us -> fl 1804416
    unsigned short* wfg = (unsigned short*)(fw + 1804416); // 4608 us

    k_pre<<<1473, 256, 0, stream>>>(emb_in, g0, b0, emb, W1, w1t,
                                    Wc, Wc1, g1, b1, wfg,
                                    ast, aed, ost, oed, sid, xv, nf, hasedge);
    dim3 gs1(24, 2, 7);
    k_skinny<<<gs1, 256, 0, stream>>>(xv, Wtp, btp, nf, 1568, 1539, 224);
    k_graph<<<64, 256, 0, stream>>>(nf, ast, aed, ost, oed, E, Wat, bat, hasin, hasedge, agg, raw);
    k_skinny<<<gs1, 256, 0, stream>>>(agg, Wg, bg, raw, 1536, 1536, 224);
    k_gemm<<<512, 64, 0, stream>>>(emb, w1t, abm, raw, nf, hasin, hasedge, ast, ost);
    dim3 g6(16, 16, 4);
    k_hidden3<<<g6, 256, 0, stream>>>(abm, bl1, masks, wfg, bc, bc1, outp);
}